// Round 1
// baseline (783.374 us; speedup 1.0000x reference)
//
#include <hip/hip_runtime.h>
#include <hip/hip_bf16.h>
#include <stdint.h>
#include <stddef.h>

// Problem constants (from reference)
#define SLEN 2048
#define BSZ  4
#define HSD  1024
#define FFND 4096
#define NEXP 8
#define NTOP 2
#define NTOK (SLEN*BSZ)        // 8192 tokens
#define NROW (NTOK*NTOP)       // 16384 (token,k) rows
#define NRP  (NROW + NEXP*256) // 18432 padded row capacity (256-row tiles)
#define MAXT (NROW/256 + NEXP) // 72 max 256-row tiles

typedef __hip_bfloat16 bf16;
typedef __attribute__((ext_vector_type(8))) __bf16 b8v;   // MFMA A/B frag (4 VGPR)
typedef __attribute__((ext_vector_type(4))) float f4v;    // MFMA C/D frag

// ---- workspace layout (bytes) ----
static constexpr size_t OFF_BLOCKHIST = 0;                        // int[64][8]
static constexpr size_t OFF_BLOCKBASE = 2048;                     // int[64][8]
static constexpr size_t OFF_SCHED_E   = 4096;                     // int[<=160]
static constexpr size_t OFF_SCHED_R   = 4736;                     // int[<=160]
static constexpr size_t OFF_NTILES    = 5376;                     // int
static constexpr size_t OFF_STOK      = 8192;                     // int[NRP]   (73728 B)
static constexpr size_t OFF_SWT       = OFF_STOK + 73728;         // float[NRP] (73728 B)
static constexpr size_t OFF_SLOT      = OFF_SWT + 73728;          // int[NROW]  (65536 B) -> ends 221184
static constexpr size_t OFF_XB        = 221184;                   // bf16[NTOK][HSD]
static constexpr size_t OFF_W1T       = OFF_XB  + (size_t)NTOK*HSD*2;        // bf16[E][FFN][HS]
static constexpr size_t OFF_W2T       = OFF_W1T + (size_t)NEXP*FFND*HSD*2;   // bf16[E][HS][FFN]
static constexpr size_t OFF_H         = OFF_W2T + (size_t)NEXP*HSD*FFND*2;   // bf16[NRP][FFN]
static constexpr size_t WS_NEED       = OFF_H   + (size_t)NRP*FFND*2;        // ~302 MiB (< prior 329 MiB check)
// Split-K partials alias the xb+w1t region (dead after GEMM1):
//   Yp = bf16[2][NRP][HSD] = 75.5 MB  <=  xb(16.8) + w1t(67.1) = 83.9 MB  OK (w2t untouched)
static constexpr size_t OFF_YP        = OFF_XB;

// ---- helpers ----
__device__ __forceinline__ void gload_lds16(const void* g, void* l) {
  __builtin_amdgcn_global_load_lds(
      (const __attribute__((address_space(1))) unsigned int*)g,
      (__attribute__((address_space(3))) unsigned int*)l, 16, 0, 0);
}

__device__ __forceinline__ f4v mfma16(b8v a, b8v b, f4v c) {
  return __builtin_amdgcn_mfma_f32_16x16x32_bf16(a, b, c, 0, 0, 0);
}

__device__ __forceinline__ float gelu_tanh(float x) {
  float u = 0.7978845608028654f * x * (1.0f + 0.044715f * x * x);
  float e = __expf(2.0f * u);
  float t = 1.0f - 2.0f / (e + 1.0f);   // tanh(u), safe at +/-inf
  return 0.5f * x * (1.0f + t);
}

// ================= routing =================
__global__ void moe_hist(const int* __restrict__ eidx, int* __restrict__ blockhist) {
  __shared__ int h[NEXP];
  int tid = threadIdx.x;
  if (tid < NEXP) h[tid] = 0;
  __syncthreads();
  int gid = blockIdx.x * 256 + tid;          // grid = 64 blocks -> 16384
  atomicAdd(&h[eidx[gid] & 7], 1);
  __syncthreads();
  if (tid < NEXP) blockhist[blockIdx.x * NEXP + tid] = h[tid];
}

__global__ void moe_plan(const int* __restrict__ blockhist, int* __restrict__ blockbase,
                         int* __restrict__ sched_e, int* __restrict__ sched_r,
                         int* __restrict__ ntiles,
                         int* __restrict__ stok, float* __restrict__ swt) {
  int tid = threadIdx.x;
  for (int i = tid; i < NRP; i += 256) { stok[i] = 0; swt[i] = 0.0f; }
  __syncthreads();
  if (tid == 0) {
    int cnt[NEXP], off[NEXP];
    for (int e = 0; e < NEXP; ++e) {
      int c = 0;
      for (int b = 0; b < 64; ++b) c += blockhist[b * NEXP + e];
      cnt[e] = c;
    }
    int run = 0, it = 0;
    for (int e = 0; e < NEXP; ++e) {
      off[e] = run;
      int nt = (cnt[e] + 255) >> 8;          // 256-row tiles
      for (int j = 0; j < nt; ++j) { sched_e[it] = e; sched_r[it] = run + j * 256; ++it; }
      run += nt << 8;
    }
    *ntiles = it;
    for (int e = 0; e < NEXP; ++e) {
      int r = off[e];
      for (int b = 0; b < 64; ++b) { blockbase[b * NEXP + e] = r; r += blockhist[b * NEXP + e]; }
    }
  }
}

__global__ void moe_scatter(const int* __restrict__ eidx, const float* __restrict__ ew,
                            const int* __restrict__ blockbase,
                            int* __restrict__ stok, float* __restrict__ swt,
                            int* __restrict__ slot) {
  __shared__ int cur[NEXP];
  int tid = threadIdx.x;
  if (tid < NEXP) cur[tid] = blockbase[blockIdx.x * NEXP + tid];
  __syncthreads();
  int gid = blockIdx.x * 256 + tid;
  int e = eidx[gid] & 7;
  int pos = atomicAdd(&cur[e], 1);
  stok[pos] = gid >> 1;          // token = gid / NTOP
  swt[pos]  = ew[gid];
  slot[gid] = pos;
}

// ================= dtype prep =================
__global__ void conv_x(const float* __restrict__ x, bf16* __restrict__ xb) {
  int gid = blockIdx.x * 256 + threadIdx.x;          // NTOK*HSD/4 threads
  float4 v = ((const float4*)x)[gid];
  alignas(8) bf16 o[4];
  o[0] = __float2bfloat16(v.x); o[1] = __float2bfloat16(v.y);
  o[2] = __float2bfloat16(v.z); o[3] = __float2bfloat16(v.w);
  ((ushort4*)xb)[gid] = *(const ushort4*)o;
}

// src [E][R][C] f32 -> dst [E][C][R] bf16.  64 rows x 32 cols per block;
// stores are packed uint (2x bf16): 32 lanes x 4 B = full 128-B lines.
__global__ void transpose_conv(const float* __restrict__ src, bf16* __restrict__ dst,
                               int R, int C) {
  __shared__ float tile[32][65];          // [col][row], pad breaks 64-stride
  int e = blockIdx.z;
  const float* s = src + (size_t)e * R * C;
  uint* d = (uint*)((ushort*)dst + (size_t)e * R * C);
  int c0 = blockIdx.x * 32, r0 = blockIdx.y * 64;
  int tx = threadIdx.x, ty = threadIdx.y;  // 32 x 8
  #pragma unroll
  for (int j = 0; j < 64; j += 8)
    tile[tx][ty + j] = s[(size_t)(r0 + ty + j) * C + (c0 + tx)];
  __syncthreads();
  #pragma unroll
  for (int j = 0; j < 32; j += 8) {
    int c = ty + j;
    alignas(4) bf16 p[2];
    p[0] = __float2bfloat16(tile[c][tx * 2]);
    p[1] = __float2bfloat16(tile[c][tx * 2 + 1]);
    d[(((size_t)(c0 + c) * R + r0) >> 1) + tx] = *(const uint*)p;
  }
}

// ================= grouped GEMM =================
// 256-row tiles, B^T-layout weights, XOR-granule-swizzled LDS (conflict-free, kept
// from prior version).  NEW: 8-wave (512-thread) blocks, double-buffered LDS with
// distance-1 prefetch and COUNTED vmcnt + raw s_barrier (no vmcnt(0) drain in the
// steady-state loop).  Per iteration:
//   B1(raw) -> STAGE(t+1 -> buf[t+1&1]) -> s_waitcnt vmcnt(TLOADS) -> B2(raw)
//   -> ds_read+MFMA from buf[t&1]
// vmcnt(TLOADS) retires exactly tile t's loads (issued last iter, covered by a full
// MFMA phase); tile t+1's TLOADS stay in flight across both barriers.
template<int KDIM, int NDIM, int BN, int NSPLIT, bool GATHER, int ACT>
__global__ __launch_bounds__(512, 2)
void moe_gemm(const bf16* __restrict__ A, const bf16* __restrict__ B,
              bf16* __restrict__ OutBase,
              const int* __restrict__ stok,
              const int* __restrict__ sched_e, const int* __restrict__ sched_r,
              const int* __restrict__ ntiles) {
  constexpr int BM = 256, BK = 64;
  constexpr int WN = BN / 64;                 // waves along N: 4 (BN=256) or 2 (BN=128)
  constexpr int WM = 8 / WN;                  // 2 or 4
  constexpr int WTM = BM / WM;                // per-wave M: 128 or 64
  constexpr int MF = WTM / 16;                // 8 or 4 m-frags
  constexpr int NF = 4;                       // per-wave N fixed 64 -> 4 n-frags
  constexpr int A_LOADS = (BM * BK) / (512 * 8);   // 4 gload_lds16 per thread
  constexpr int B_LOADS = (BN * BK) / (512 * 8);   // 4 or 2
  constexpr int TLOADS  = A_LOADS + B_LOADS;       // 8 or 6
  constexpr int BUFS = (BM + BN) * BK;             // shorts per buffer

  int rt = blockIdx.y;
  if (rt >= *ntiles) return;
  const int tid  = threadIdx.x;
  const int lane = tid & 63;
  const int wid  = tid >> 6;
  const int wm = wid % WM, wn = wid / WM;
  const int e    = sched_e[rt];
  const int row0 = sched_r[rt];
  const int n0   = blockIdx.x * BN;
  const int z    = blockIdx.z;
  const int kbase = z * (KDIM / NSPLIT);
  bf16* Out = OutBase + (size_t)z * NRP * NDIM;

  __shared__ short lds[2 * BUFS];             // 128 KB (BN=256) / 96 KB (BN=128)

  const int l15  = lane & 15;
  const int quad = lane >> 4;
  const ushort* Aus = (const ushort*)A;
  const ushort* Bexp = (const ushort*)B + (size_t)e * NDIM * KDIM;

  // ---- staging pointers (coalesced, swizzle folded into global k-offset) ----
  const int rsub  = lane >> 3;                 // 0..7: row within 1KB chunk
  const int kgsrc = (lane & 7) ^ rsub;         // granule permutation (same line)
  const ushort* aptr[A_LOADS];
  const ushort* bptr[B_LOADS];
  #pragma unroll
  for (int j = 0; j < A_LOADS; ++j) {
    int i  = wid * A_LOADS + j;                // chunk 0..31: rows 8i..8i+7
    int xr = 8 * i + rsub;
    int grow = GATHER ? stok[row0 + xr] : (row0 + xr);
    aptr[j] = Aus  + (size_t)grow * KDIM + kbase + kgsrc * 8;
  }
  #pragma unroll
  for (int j = 0; j < B_LOADS; ++j) {
    int i  = wid * B_LOADS + j;
    int xr = 8 * i + rsub;
    bptr[j] = Bexp + (size_t)(n0 + xr) * KDIM + kbase + kgsrc * 8;
  }

  // ---- compute-side LDS offsets (shorts), constant across K ----
  int aoff[MF][2], boff[NF][2];
  #pragma unroll
  for (int t = 0; t < MF; ++t) {
    int m_local = wm * WTM + t * 16 + l15;
    #pragma unroll
    for (int s = 0; s < 2; ++s) {
      int kg = s * 4 + quad;
      aoff[t][s] = m_local * 64 + ((kg ^ (l15 & 7)) << 3);
    }
  }
  #pragma unroll
  for (int t = 0; t < NF; ++t) {
    int n_local = wn * 64 + t * 16 + l15;
    #pragma unroll
    for (int s = 0; s < 2; ++s) {
      int kg = s * 4 + quad;
      boff[t][s] = n_local * 64 + ((kg ^ (l15 & 7)) << 3);
    }
  }

  f4v acc[MF][NF];
  #pragma unroll
  for (int mt = 0; mt < MF; ++mt)
    #pragma unroll
    for (int nt = 0; nt < NF; ++nt) acc[mt][nt] = (f4v)0.0f;

  auto STAGE = [&](int par) {
    short* ab = lds + par * BUFS;
    short* bb = ab + BM * BK;
    #pragma unroll
    for (int j = 0; j < A_LOADS; ++j) {
      gload_lds16(aptr[j], ab + (wid * A_LOADS + j) * 512);
      aptr[j] += BK;
    }
    #pragma unroll
    for (int j = 0; j < B_LOADS; ++j) {
      gload_lds16(bptr[j], bb + (wid * B_LOADS + j) * 512);
      bptr[j] += BK;
    }
  };

  STAGE(0);                                  // prologue: tile 0 in flight
  const int KT = KDIM / BK / NSPLIT;
  #pragma unroll 2
  for (int kt = 0; kt < KT; ++kt) {
    asm volatile("" ::: "memory");           // keep prev-iter ds_reads above B1
    __builtin_amdgcn_s_barrier();            // B1: all waves done reading buf[(kt+1)&1]
    if (kt + 1 < KT) {
      STAGE((kt + 1) & 1);
      if constexpr (TLOADS == 8) asm volatile("s_waitcnt vmcnt(8)" ::: "memory");
      else                       asm volatile("s_waitcnt vmcnt(6)" ::: "memory");
    } else {
      asm volatile("s_waitcnt vmcnt(0)" ::: "memory");
    }
    __builtin_amdgcn_s_barrier();            // B2: tile kt visible to all waves
    const short* Ab = lds + (kt & 1) * BUFS;
    const short* Bb = Ab + BM * BK;
    __builtin_amdgcn_s_setprio(1);
    #pragma unroll
    for (int s = 0; s < 2; ++s) {
      b8v af[MF], bfm[NF];
      #pragma unroll
      for (int mt = 0; mt < MF; ++mt)
        af[mt] = *(const b8v*)(Ab + aoff[mt][s]);
      #pragma unroll
      for (int nt = 0; nt < NF; ++nt)
        bfm[nt] = *(const b8v*)(Bb + boff[nt][s]);
      #pragma unroll
      for (int mt = 0; mt < MF; ++mt)
        #pragma unroll
        for (int nt = 0; nt < NF; ++nt)
          acc[mt][nt] = mfma16(af[mt], bfm[nt], acc[mt][nt]);
    }
    __builtin_amdgcn_s_setprio(0);
  }

  // epilogue: C/D layout row=(lane>>4)*4+reg, col=lane&15  [m89-verified]
  #pragma unroll
  for (int mt = 0; mt < MF; ++mt)
    #pragma unroll
    for (int nt = 0; nt < NF; ++nt) {
      f4v v = acc[mt][nt];
      #pragma unroll
      for (int r = 0; r < 4; ++r) {
        int m = row0 + wm * WTM + mt * 16 + quad * 4 + r;
        int n = n0   + wn * 64 + nt * 16 + l15;
        float o = (ACT == 0) ? gelu_tanh(v[r]) : v[r];
        Out[(size_t)m * NDIM + n] = __float2bfloat16(o);
      }
    }
}

// ================= combine =================
// out[t] = swt[s0]*(Yp0[s0]+Yp1[s0]) + swt[s1]*(Yp0[s1]+Yp1[s1])
__global__ void moe_combine(const bf16* __restrict__ Yp, const float* __restrict__ swt,
                            const int* __restrict__ slot, float* __restrict__ out) {
  int gid = blockIdx.x * 256 + threadIdx.x;   // NTOK*HSD/8 threads
  int t  = gid >> 7;
  int ho = (gid & 127) << 3;
  int s0 = slot[t * 2], s1 = slot[t * 2 + 1];
  float w0 = swt[s0], w1 = swt[s1];
  const __bf16* Y0 = (const __bf16*)Yp;
  const __bf16* Y1 = Y0 + (size_t)NRP * HSD;
  b8v a0 = *(const b8v*)(Y0 + (size_t)s0 * HSD + ho);
  b8v a1 = *(const b8v*)(Y1 + (size_t)s0 * HSD + ho);
  b8v b0 = *(const b8v*)(Y0 + (size_t)s1 * HSD + ho);
  b8v b1 = *(const b8v*)(Y1 + (size_t)s1 * HSD + ho);
  float o[8];
  #pragma unroll
  for (int i = 0; i < 8; ++i)
    o[i] = w0 * ((float)a0[i] + (float)a1[i]) + w1 * ((float)b0[i] + (float)b1[i]);
  float4* op = (float4*)(out + (size_t)t * HSD + ho);
  op[0] = make_float4(o[0], o[1], o[2], o[3]);
  op[1] = make_float4(o[4], o[5], o[6], o[7]);
}

// ================= launch =================
extern "C" void kernel_launch(void* const* d_in, const int* in_sizes, int n_in,
                              void* d_out, int out_size, void* d_ws, size_t ws_size,
                              hipStream_t stream) {
  const float* x    = (const float*)d_in[0];
  const float* ew   = (const float*)d_in[1];
  const float* w1   = (const float*)d_in[2];
  const float* w2   = (const float*)d_in[3];
  const int*   eidx = (const int*)d_in[4];
  float* out = (float*)d_out;
  char* ws = (char*)d_ws;

  if (ws_size < WS_NEED) {              // sentinel: absmax ~3.4e38 => ws too small
    hipMemsetAsync(d_out, 0x7F, 8, stream);
    return;
  }

  int*   blockhist = (int*)(ws + OFF_BLOCKHIST);
  int*   blockbase = (int*)(ws + OFF_BLOCKBASE);
  int*   sched_e   = (int*)(ws + OFF_SCHED_E);
  int*   sched_r   = (int*)(ws + OFF_SCHED_R);
  int*   ntiles    = (int*)(ws + OFF_NTILES);
  int*   stok      = (int*)(ws + OFF_STOK);
  float* swt       = (float*)(ws + OFF_SWT);
  int*   slot      = (int*)(ws + OFF_SLOT);
  bf16*  xb        = (bf16*)(ws + OFF_XB);
  bf16*  w1t       = (bf16*)(ws + OFF_W1T);
  bf16*  w2t       = (bf16*)(ws + OFF_W2T);
  bf16*  Hbuf      = (bf16*)(ws + OFF_H);
  bf16*  Ypart     = (bf16*)(ws + OFF_YP);   // aliases xb/w1t (dead after GEMM1)

  moe_hist<<<64, 256, 0, stream>>>(eidx, blockhist);
  moe_plan<<<1, 256, 0, stream>>>(blockhist, blockbase, sched_e, sched_r, ntiles, stok, swt);
  moe_scatter<<<64, 256, 0, stream>>>(eidx, ew, blockbase, stok, swt, slot);

  conv_x<<<(NTOK * HSD / 4) / 256, 256, 0, stream>>>(x, xb);
  transpose_conv<<<dim3(FFND / 32, HSD / 64, NEXP), dim3(32, 8), 0, stream>>>(w1, w1t, HSD, FFND);
  transpose_conv<<<dim3(HSD / 32, FFND / 64, NEXP), dim3(32, 8), 0, stream>>>(w2, w2t, FFND, HSD);

  // GEMM1: H = gelu(X @ W1), gathered rows, K=1024, 256x256 tiles
  moe_gemm<HSD, FFND, 256, 1, true, 0><<<dim3(FFND / 256, MAXT, 1), 512, 0, stream>>>(
      xb, w1t, Hbuf, stok, sched_e, sched_r, ntiles);
  // GEMM2: Yp[z] = H @ W2 (split-K=2 partials, unweighted), 256x128 tiles
  moe_gemm<FFND, HSD, 128, 2, false, 1><<<dim3(HSD / 128, MAXT, 2), 512, 0, stream>>>(
      Hbuf, w2t, Ypart, stok, sched_e, sched_r, ntiles);

  moe_combine<<<NTOK * HSD / 8 / 256, 256, 0, stream>>>(Ypart, swt, slot, out);
}

// Round 2
// 734.673 us; speedup vs baseline: 1.0663x; 1.0663x over previous
//
#include <hip/hip_runtime.h>
#include <hip/hip_bf16.h>
#include <stdint.h>
#include <stddef.h>

// Problem constants (from reference)
#define SLEN 2048
#define BSZ  4
#define HSD  1024
#define FFND 4096
#define NEXP 8
#define NTOP 2
#define NTOK (SLEN*BSZ)        // 8192 tokens
#define NROW (NTOK*NTOP)       // 16384 (token,k) rows
#define NRP  (NROW + NEXP*256) // 18432 padded row capacity (256-row tiles)
#define MAXT (NROW/256 + NEXP) // 72 max 256-row tiles

typedef __hip_bfloat16 bf16;
typedef __attribute__((ext_vector_type(8))) __bf16 b8v;   // MFMA A/B frag (4 VGPR)
typedef __attribute__((ext_vector_type(4))) float f4v;    // MFMA C/D frag

// ---- workspace layout (bytes) ----
static constexpr size_t OFF_BLOCKHIST = 0;                        // int[64][8]
static constexpr size_t OFF_BLOCKBASE = 2048;                     // int[64][8]
static constexpr size_t OFF_SCHED_E   = 4096;                     // int[<=160]
static constexpr size_t OFF_SCHED_R   = 4736;                     // int[<=160]
static constexpr size_t OFF_NTILES    = 5376;                     // int
static constexpr size_t OFF_STOK      = 8192;                     // int[NRP]   (73728 B)
static constexpr size_t OFF_SWT       = OFF_STOK + 73728;         // float[NRP] (73728 B)
static constexpr size_t OFF_SLOT      = OFF_SWT + 73728;          // int[NROW]  (65536 B) -> ends 221184
static constexpr size_t OFF_XB        = 221184;                   // bf16[NTOK][HSD]
static constexpr size_t OFF_W1T       = OFF_XB  + (size_t)NTOK*HSD*2;        // bf16[E][FFN][HS]
static constexpr size_t OFF_W2T       = OFF_W1T + (size_t)NEXP*FFND*HSD*2;   // bf16[E][HS][FFN]
static constexpr size_t OFF_H         = OFF_W2T + (size_t)NEXP*HSD*FFND*2;   // bf16[NRP][FFN]
static constexpr size_t WS_NEED       = OFF_H   + (size_t)NRP*FFND*2;        // ~302 MiB
// Split-K partials alias the xb+w1t region (dead after GEMM1):
//   Yp = bf16[2][NRP][HSD] = 75.5 MB  <=  xb(16.8) + w1t(67.1) = 83.9 MB  OK (w2t untouched)
static constexpr size_t OFF_YP        = OFF_XB;

// ---- helpers ----
__device__ __forceinline__ void gload_lds16(const void* g, void* l) {
  __builtin_amdgcn_global_load_lds(
      (const __attribute__((address_space(1))) unsigned int*)g,
      (__attribute__((address_space(3))) unsigned int*)l, 16, 0, 0);
}

__device__ __forceinline__ f4v mfma16(b8v a, b8v b, f4v c) {
  return __builtin_amdgcn_mfma_f32_16x16x32_bf16(a, b, c, 0, 0, 0);
}

__device__ __forceinline__ float gelu_tanh(float x) {
  float u = 0.7978845608028654f * x * (1.0f + 0.044715f * x * x);
  float e = __expf(2.0f * u);
  float t = 1.0f - 2.0f / (e + 1.0f);   // tanh(u), safe at +/-inf
  return 0.5f * x * (1.0f + t);
}

// ================= routing =================
__global__ void moe_hist(const int* __restrict__ eidx, int* __restrict__ blockhist) {
  __shared__ int h[NEXP];
  int tid = threadIdx.x;
  if (tid < NEXP) h[tid] = 0;
  __syncthreads();
  int gid = blockIdx.x * 256 + tid;          // grid = 64 blocks -> 16384
  atomicAdd(&h[eidx[gid] & 7], 1);
  __syncthreads();
  if (tid < NEXP) blockhist[blockIdx.x * NEXP + tid] = h[tid];
}

__global__ void moe_plan(const int* __restrict__ blockhist, int* __restrict__ blockbase,
                         int* __restrict__ sched_e, int* __restrict__ sched_r,
                         int* __restrict__ ntiles,
                         int* __restrict__ stok, float* __restrict__ swt) {
  int tid = threadIdx.x;
  for (int i = tid; i < NRP; i += 256) { stok[i] = 0; swt[i] = 0.0f; }
  __syncthreads();
  if (tid == 0) {
    int cnt[NEXP], off[NEXP];
    for (int e = 0; e < NEXP; ++e) {
      int c = 0;
      for (int b = 0; b < 64; ++b) c += blockhist[b * NEXP + e];
      cnt[e] = c;
    }
    int run = 0, it = 0;
    for (int e = 0; e < NEXP; ++e) {
      off[e] = run;
      int nt = (cnt[e] + 255) >> 8;          // 256-row tiles
      for (int j = 0; j < nt; ++j) { sched_e[it] = e; sched_r[it] = run + j * 256; ++it; }
      run += nt << 8;
    }
    *ntiles = it;
    for (int e = 0; e < NEXP; ++e) {
      int r = off[e];
      for (int b = 0; b < 64; ++b) { blockbase[b * NEXP + e] = r; r += blockhist[b * NEXP + e]; }
    }
  }
}

__global__ void moe_scatter(const int* __restrict__ eidx, const float* __restrict__ ew,
                            const int* __restrict__ blockbase,
                            int* __restrict__ stok, float* __restrict__ swt,
                            int* __restrict__ slot) {
  __shared__ int cur[NEXP];
  int tid = threadIdx.x;
  if (tid < NEXP) cur[tid] = blockbase[blockIdx.x * NEXP + tid];
  __syncthreads();
  int gid = blockIdx.x * 256 + tid;
  int e = eidx[gid] & 7;
  int pos = atomicAdd(&cur[e], 1);
  stok[pos] = gid >> 1;          // token = gid / NTOP
  swt[pos]  = ew[gid];
  slot[gid] = pos;
}

// ================= dtype prep =================
__global__ void conv_x(const float* __restrict__ x, bf16* __restrict__ xb) {
  int gid = blockIdx.x * 256 + threadIdx.x;          // NTOK*HSD/4 threads
  float4 v = ((const float4*)x)[gid];
  alignas(8) bf16 o[4];
  o[0] = __float2bfloat16(v.x); o[1] = __float2bfloat16(v.y);
  o[2] = __float2bfloat16(v.z); o[3] = __float2bfloat16(v.w);
  ((ushort4*)xb)[gid] = *(const ushort4*)o;
}

// src [E][R][C] f32 -> dst [E][C][R] bf16.
__global__ void transpose_conv(const float* __restrict__ src, bf16* __restrict__ dst,
                               int R, int C) {
  __shared__ float tile[32][65];          // [col][row], pad breaks 64-stride
  int e = blockIdx.z;
  const float* s = src + (size_t)e * R * C;
  uint* d = (uint*)((ushort*)dst + (size_t)e * R * C);
  int c0 = blockIdx.x * 32, r0 = blockIdx.y * 64;
  int tx = threadIdx.x, ty = threadIdx.y;  // 32 x 8
  #pragma unroll
  for (int j = 0; j < 64; j += 8)
    tile[tx][ty + j] = s[(size_t)(r0 + ty + j) * C + (c0 + tx)];
  __syncthreads();
  #pragma unroll
  for (int j = 0; j < 32; j += 8) {
    int c = ty + j;
    alignas(4) bf16 p[2];
    p[0] = __float2bfloat16(tile[c][tx * 2]);
    p[1] = __float2bfloat16(tile[c][tx * 2 + 1]);
    d[(((size_t)(c0 + c) * R + r0) >> 1) + tx] = *(const uint*)p;
  }
}

// ================= grouped GEMM: 256x256 8-phase schedule (m201 template) =====
// 8 waves (2M x 4N), per-wave C = 128x64.  LDS = 2 K-tile buffers x 64KB.
// Half-tiles: A-half = 128 rows x 64 K (16 KB, 2 gload_lds16/thread), B same.
// Per iteration j (tiles 2j->buf0, 2j+1->buf1), 8 phases; each phase:
//   [ds-read quadrant frags | stage 1 half-tile] -> barrier -> 16 MFMA -> barrier
// Quadrant order per tile: (qm,qn) = (0,0),(0,1),(1,1),(1,0); reads/phase 12/4/8/0
// (both B n-half frag sets kept in regs across the tile; A re-read per m-half).
// Stage stream p0..p7: b1.A0<-t1, b1.A1<-t1, b0.B0<-t2, b0.B1<-t2,
//                      b0.A0<-t2, b0.A1<-t2, b1.B0<-t3, b1.B1<-t3
// Deaths: B-halves die p1/p5, A-halves p2/p6 (of their tile's 4 phases) -> all
// stages overwrite dead slots.  Landing: counted s_waitcnt vmcnt(4) before the
// end-barrier of p3 and p7 only (2-6 half-tiles in flight, never drained to 0
// except p3 of the final iteration, whose p2..p7 prefetches are disabled).
template<int KDIM, int NDIM, int NSPLIT, bool GATHER, int ACT>
__global__ __launch_bounds__(512, 2)
void moe_gemm(const bf16* __restrict__ A, const bf16* __restrict__ B,
              bf16* __restrict__ OutBase,
              const int* __restrict__ stok,
              const int* __restrict__ sched_e, const int* __restrict__ sched_r,
              const int* __restrict__ ntiles) {
  constexpr int BM = 256, BN = 256, BK = 64;
  constexpr int BUFS = (BM + BN) * BK;        // 32768 shorts = 64 KB per K-tile
  constexpr int KT = KDIM / BK / NSPLIT;      // 16 (GEMM1) / 32 (GEMM2)
  constexpr int JT = KT / 2;

  int rt = blockIdx.y;
  if (rt >= *ntiles) return;
  const int tid  = threadIdx.x;
  const int lane = tid & 63;
  const int wid  = tid >> 6;                  // 0..7
  const int wm = wid & 1, wn = wid >> 1;      // 2M x 4N
  const int e    = sched_e[rt];
  const int row0 = sched_r[rt];
  const int n0   = blockIdx.x * BN;
  const int z    = blockIdx.z;
  const int kbase = z * (KDIM / NSPLIT);
  bf16* Out = OutBase + (size_t)z * NRP * NDIM;

  __shared__ short lds[2 * BUFS];             // 128 KB

  const int l15  = lane & 15;
  const int quad = lane >> 4;
  const int xor7 = l15 & 7;
  const ushort* Aus  = (const ushort*)A;
  const ushort* Bexp = (const ushort*)B + (size_t)e * NDIM * KDIM;

  // ---- staging pointers (coalesced; swizzle folded into global k-offset) ----
  const int rsub  = lane >> 3;                 // row within 8-row chunk
  const int kgsrc = (lane & 7) ^ rsub;         // granule permutation (same line)
  const ushort* aP[2][2];                      // [half][q]
  const ushort* bP[2][2];
  #pragma unroll
  for (int h = 0; h < 2; ++h)
    #pragma unroll
    for (int q = 0; q < 2; ++q) {
      int xr = 128 * h + 8 * (2 * wid + q) + rsub;
      int grow = GATHER ? stok[row0 + xr] : (row0 + xr);
      aP[h][q] = Aus  + (size_t)grow * KDIM + kbase + kgsrc * 8;
      bP[h][q] = Bexp + (size_t)(n0 + xr) * KDIM + kbase + kgsrc * 8;
    }

  // stage one A/B half-tile of K-tile T into buffer b (2 x gload_lds16/thread)
  auto SA = [&](int b, int h, int T) {
    #pragma unroll
    for (int q = 0; q < 2; ++q)
      gload_lds16(aP[h][q] + T * 64, lds + b * BUFS + h * 8192 + (2 * wid + q) * 512);
  };
  auto SB = [&](int b, int h, int T) {
    #pragma unroll
    for (int q = 0; q < 2; ++q)
      gload_lds16(bP[h][q] + T * 64, lds + b * BUFS + BM * BK + h * 8192 + (2 * wid + q) * 512);
  };

  // ---- compute-side LDS addressing (shorts) ----
  const int goff0 = (quad ^ xor7) << 3;            // k-slice 0 granule offset
  const int goff1 = ((4 + quad) ^ xor7) << 3;      // k-slice 1
  const int mbase = (wm * 128 + l15) * 64;         // A rows base
  const int nbase = BM * BK + (wn * 64 + l15) * 64;// B region base

  f4v acc[8][4];
  #pragma unroll
  for (int mt = 0; mt < 8; ++mt)
    #pragma unroll
    for (int nt = 0; nt < 4; ++nt) acc[mt][nt] = (f4v)0.0f;

  b8v aF[2][4], bF0[2][2], bF1[2][2];

  auto LDA = [&](int b, int qm) {
    const short* base = lds + b * BUFS + mbase + qm * 4096;
    #pragma unroll
    for (int t = 0; t < 4; ++t) {
      aF[0][t] = *(const b8v*)(base + t * 1024 + goff0);
      aF[1][t] = *(const b8v*)(base + t * 1024 + goff1);
    }
  };
  auto LDB = [&](int b, int qn, b8v (&bF)[2][2]) {
    const short* base = lds + b * BUFS + nbase + qn * 2048;
    #pragma unroll
    for (int u = 0; u < 2; ++u) {
      bF[0][u] = *(const b8v*)(base + u * 1024 + goff0);
      bF[1][u] = *(const b8v*)(base + u * 1024 + goff1);
    }
  };
  auto MM = [&](int qm, int qn, b8v (&bF)[2][2]) {
    __builtin_amdgcn_s_setprio(1);
    #pragma unroll
    for (int s = 0; s < 2; ++s)
      #pragma unroll
      for (int t = 0; t < 4; ++t)
        #pragma unroll
        for (int u = 0; u < 2; ++u)
          acc[qm * 4 + t][qn * 2 + u] = mfma16(aF[s][t], bF[s][u], acc[qm * 4 + t][qn * 2 + u]);
    __builtin_amdgcn_s_setprio(0);
  };
  auto BAR = [&] {
    asm volatile("" ::: "memory");
    __builtin_amdgcn_s_barrier();
    asm volatile("" ::: "memory");
  };

  // ---- prologue: tile0 full + tile1 B-halves (steady-state p2..p7 of iter -1)
  SB(0, 0, 0); SB(0, 1, 0); SA(0, 0, 0); SA(0, 1, 0);
  SB(1, 0, 1); SB(1, 1, 1);
  asm volatile("s_waitcnt vmcnt(4)" ::: "memory");   // tile0 halves landed
  __builtin_amdgcn_s_barrier();
  asm volatile("" ::: "memory");

  #pragma unroll 1
  for (int j = 0; j < JT; ++j) {
    const int t1 = 2 * j + 1, t2 = 2 * j + 2, t3 = 2 * j + 3;
    const bool more = (j + 1 < JT);
    // ---- p0: buf0 quad (0,0); stage b1.A0 <- t1
    LDA(0, 0); LDB(0, 0, bF0);
    SA(1, 0, t1);
    BAR(); MM(0, 0, bF0); BAR();
    // ---- p1: buf0 quad (0,1); stage b1.A1 <- t1
    LDB(0, 1, bF1);
    SA(1, 1, t1);
    BAR(); MM(0, 1, bF1); BAR();
    // ---- p2: buf0 quad (1,1); stage b0.B0 <- t2
    LDA(0, 1);
    if (more) SB(0, 0, t2);
    BAR(); MM(1, 1, bF1); BAR();
    // ---- p3: buf0 quad (1,0); stage b0.B1 <- t2; checkpoint
    if (more) SB(0, 1, t2);
    BAR(); MM(1, 0, bF0);
    if (more) asm volatile("s_waitcnt vmcnt(4)" ::: "memory");
    else      asm volatile("s_waitcnt vmcnt(0)" ::: "memory");
    BAR();
    // ---- p4: buf1 quad (0,0); stage b0.A0 <- t2
    LDA(1, 0); LDB(1, 0, bF0);
    if (more) SA(0, 0, t2);
    BAR(); MM(0, 0, bF0); BAR();
    // ---- p5: buf1 quad (0,1); stage b0.A1 <- t2
    LDB(1, 1, bF1);
    if (more) SA(0, 1, t2);
    BAR(); MM(0, 1, bF1); BAR();
    // ---- p6: buf1 quad (1,1); stage b1.B0 <- t3
    LDA(1, 1);
    if (more) SB(1, 0, t3);
    BAR(); MM(1, 1, bF1); BAR();
    // ---- p7: buf1 quad (1,0); stage b1.B1 <- t3; checkpoint
    if (more) SB(1, 1, t3);
    BAR(); MM(1, 0, bF0);
    asm volatile("s_waitcnt vmcnt(4)" ::: "memory");
    BAR();
  }

  // epilogue: C/D layout row=(lane>>4)*4+reg, col=lane&15  [m89-verified]
  #pragma unroll
  for (int mt = 0; mt < 8; ++mt)
    #pragma unroll
    for (int nt = 0; nt < 4; ++nt) {
      f4v v = acc[mt][nt];
      #pragma unroll
      for (int r = 0; r < 4; ++r) {
        int m = row0 + wm * 128 + mt * 16 + quad * 4 + r;
        int n = n0   + wn * 64  + nt * 16 + l15;
        float o = (ACT == 0) ? gelu_tanh(v[r]) : v[r];
        Out[(size_t)m * NDIM + n] = __float2bfloat16(o);
      }
    }
}

// ================= combine =================
// out[t] = swt[s0]*(Yp0[s0]+Yp1[s0]) + swt[s1]*(Yp0[s1]+Yp1[s1])
__global__ void moe_combine(const bf16* __restrict__ Yp, const float* __restrict__ swt,
                            const int* __restrict__ slot, float* __restrict__ out) {
  int gid = blockIdx.x * 256 + threadIdx.x;   // NTOK*HSD/8 threads
  int t  = gid >> 7;
  int ho = (gid & 127) << 3;
  int s0 = slot[t * 2], s1 = slot[t * 2 + 1];
  float w0 = swt[s0], w1 = swt[s1];
  const __bf16* Y0 = (const __bf16*)Yp;
  const __bf16* Y1 = Y0 + (size_t)NRP * HSD;
  b8v a0 = *(const b8v*)(Y0 + (size_t)s0 * HSD + ho);
  b8v a1 = *(const b8v*)(Y1 + (size_t)s0 * HSD + ho);
  b8v b0 = *(const b8v*)(Y0 + (size_t)s1 * HSD + ho);
  b8v b1 = *(const b8v*)(Y1 + (size_t)s1 * HSD + ho);
  float o[8];
  #pragma unroll
  for (int i = 0; i < 8; ++i)
    o[i] = w0 * ((float)a0[i] + (float)a1[i]) + w1 * ((float)b0[i] + (float)b1[i]);
  float4* op = (float4*)(out + (size_t)t * HSD + ho);
  op[0] = make_float4(o[0], o[1], o[2], o[3]);
  op[1] = make_float4(o[4], o[5], o[6], o[7]);
}

// ================= launch =================
extern "C" void kernel_launch(void* const* d_in, const int* in_sizes, int n_in,
                              void* d_out, int out_size, void* d_ws, size_t ws_size,
                              hipStream_t stream) {
  const float* x    = (const float*)d_in[0];
  const float* ew   = (const float*)d_in[1];
  const float* w1   = (const float*)d_in[2];
  const float* w2   = (const float*)d_in[3];
  const int*   eidx = (const int*)d_in[4];
  float* out = (float*)d_out;
  char* ws = (char*)d_ws;

  if (ws_size < WS_NEED) {              // sentinel: absmax ~3.4e38 => ws too small
    hipMemsetAsync(d_out, 0x7F, 8, stream);
    return;
  }

  int*   blockhist = (int*)(ws + OFF_BLOCKHIST);
  int*   blockbase = (int*)(ws + OFF_BLOCKBASE);
  int*   sched_e   = (int*)(ws + OFF_SCHED_E);
  int*   sched_r   = (int*)(ws + OFF_SCHED_R);
  int*   ntiles    = (int*)(ws + OFF_NTILES);
  int*   stok      = (int*)(ws + OFF_STOK);
  float* swt       = (float*)(ws + OFF_SWT);
  int*   slot      = (int*)(ws + OFF_SLOT);
  bf16*  xb        = (bf16*)(ws + OFF_XB);
  bf16*  w1t       = (bf16*)(ws + OFF_W1T);
  bf16*  w2t       = (bf16*)(ws + OFF_W2T);
  bf16*  Hbuf      = (bf16*)(ws + OFF_H);
  bf16*  Ypart     = (bf16*)(ws + OFF_YP);   // aliases xb/w1t (dead after GEMM1)

  moe_hist<<<64, 256, 0, stream>>>(eidx, blockhist);
  moe_plan<<<1, 256, 0, stream>>>(blockhist, blockbase, sched_e, sched_r, ntiles, stok, swt);
  moe_scatter<<<64, 256, 0, stream>>>(eidx, ew, blockbase, stok, swt, slot);

  conv_x<<<(NTOK * HSD / 4) / 256, 256, 0, stream>>>(x, xb);
  transpose_conv<<<dim3(FFND / 32, HSD / 64, NEXP), dim3(32, 8), 0, stream>>>(w1, w1t, HSD, FFND);
  transpose_conv<<<dim3(HSD / 32, FFND / 64, NEXP), dim3(32, 8), 0, stream>>>(w2, w2t, FFND, HSD);

  // GEMM1: H = gelu(X @ W1), gathered rows, K=1024, 256x256 tiles, 8-phase
  moe_gemm<HSD, FFND, 1, true, 0><<<dim3(FFND / 256, MAXT, 1), 512, 0, stream>>>(
      xb, w1t, Hbuf, stok, sched_e, sched_r, ntiles);
  // GEMM2: Yp[z] = H @ W2 (split-K=2 partials, unweighted), 256x256 tiles, 8-phase
  moe_gemm<FFND, HSD, 2, false, 1><<<dim3(HSD / 256, MAXT, 2), 512, 0, stream>>>(
      Hbuf, w2t, Ypart, stok, sched_e, sched_r, ntiles);

  moe_combine<<<NTOK * HSD / 8 / 256, 256, 0, stream>>>(Ypart, swt, slot, out);
}

// Round 3
// 701.654 us; speedup vs baseline: 1.1165x; 1.0471x over previous
//
#include <hip/hip_runtime.h>
#include <hip/hip_bf16.h>
#include <stdint.h>
#include <stddef.h>

// Problem constants (from reference)
#define SLEN 2048
#define BSZ  4
#define HSD  1024
#define FFND 4096
#define NEXP 8
#define NTOP 2
#define NTOK (SLEN*BSZ)        // 8192 tokens
#define NROW (NTOK*NTOP)       // 16384 (token,k) rows
#define NRP  (NROW + NEXP*256) // 18432 padded row capacity (256-row tiles)
#define MAXT (NROW/256 + NEXP) // 72 max 256-row tiles

typedef __hip_bfloat16 bf16;
typedef __attribute__((ext_vector_type(8))) __bf16 b8v;   // MFMA A/B frag (4 VGPR)
typedef __attribute__((ext_vector_type(4))) float f4v;    // MFMA C/D frag

// ---- workspace layout (bytes) ----
static constexpr size_t OFF_BLOCKHIST = 0;                        // int[64][8]
static constexpr size_t OFF_BLOCKBASE = 2048;                     // int[64][8]
static constexpr size_t OFF_SCHED_E   = 4096;                     // int[<=160]
static constexpr size_t OFF_SCHED_R   = 4736;                     // int[<=160]
static constexpr size_t OFF_NTILES    = 5376;                     // int
static constexpr size_t OFF_STOK      = 8192;                     // int[NRP]   (73728 B)
static constexpr size_t OFF_SWT       = OFF_STOK + 73728;         // float[NRP] (73728 B)
static constexpr size_t OFF_SLOT      = OFF_SWT + 73728;          // int[NROW]  (65536 B) -> ends 221184
static constexpr size_t OFF_XB        = 221184;                   // bf16[NTOK][HSD]
static constexpr size_t OFF_W1T       = OFF_XB  + (size_t)NTOK*HSD*2;        // bf16[E][FFN][HS]
static constexpr size_t OFF_W2T       = OFF_W1T + (size_t)NEXP*FFND*HSD*2;   // bf16[E][HS][FFN]
static constexpr size_t OFF_H         = OFF_W2T + (size_t)NEXP*HSD*FFND*2;   // bf16[NRP][FFN]
static constexpr size_t WS_NEED       = OFF_H   + (size_t)NRP*FFND*2;        // ~302 MiB
// Split-K partials alias the xb+w1t region (dead after GEMM1):
//   Yp = bf16[2][NRP][HSD] = 75.5 MB  <=  xb(16.8) + w1t(67.1) = 83.9 MB  OK (w2t untouched)
static constexpr size_t OFF_YP        = OFF_XB;

// ---- helpers ----
__device__ __forceinline__ void gload_lds16(const void* g, void* l) {
  __builtin_amdgcn_global_load_lds(
      (const __attribute__((address_space(1))) unsigned int*)g,
      (__attribute__((address_space(3))) unsigned int*)l, 16, 0, 0);
}

__device__ __forceinline__ f4v mfma16(b8v a, b8v b, f4v c) {
  return __builtin_amdgcn_mfma_f32_16x16x32_bf16(a, b, c, 0, 0, 0);
}

__device__ __forceinline__ float gelu_tanh(float x) {
  float u = 0.7978845608028654f * x * (1.0f + 0.044715f * x * x);
  float e = __expf(2.0f * u);
  float t = 1.0f - 2.0f / (e + 1.0f);   // tanh(u), safe at +/-inf
  return 0.5f * x * (1.0f + t);
}

// ================= fused prep: conv_x + w1^T + w2^T + hist =================
// One launch; grid sections.  Saves 3 launch gaps and overlaps the streams.
#define NB_CONV (NTOK*HSD/4/256)                 // 8192
#define NB_W1   (NEXP*(HSD/64)*(FFND/32))        // 16384
#define NB_W2   (NEXP*(FFND/64)*(HSD/32))        // 16384
#define NB_HIST 64
#define NB_PREP (NB_CONV + NB_W1 + NB_W2 + NB_HIST)

template<int R, int C>
__device__ __forceinline__ void transpose_body(const float* __restrict__ src,
                                               bf16* __restrict__ dst,
                                               int l, int tid) {
  __shared__ float tile[32][65];          // [col][row], pad breaks 64-stride
  constexpr int CT = C / 32, RT = R / 64;          // both pow2
  int e   = l / (CT * RT);
  int rem = l - e * (CT * RT);
  int by  = rem / CT, bx = rem % CT;
  const float* s = src + (size_t)e * R * C;
  uint* d = (uint*)((ushort*)dst + (size_t)e * R * C);
  int c0 = bx * 32, r0 = by * 64;
  int tx = tid & 31, ty = tid >> 5;        // 32 x 8
  #pragma unroll
  for (int j = 0; j < 64; j += 8)
    tile[tx][ty + j] = s[(size_t)(r0 + ty + j) * C + (c0 + tx)];
  __syncthreads();
  #pragma unroll
  for (int j = 0; j < 32; j += 8) {
    int c = ty + j;
    alignas(4) bf16 p[2];
    p[0] = __float2bfloat16(tile[c][tx * 2]);
    p[1] = __float2bfloat16(tile[c][tx * 2 + 1]);
    d[(((size_t)(c0 + c) * R + r0) >> 1) + tx] = *(const uint*)p;
  }
}

__global__ void moe_prep(const float* __restrict__ x, bf16* __restrict__ xb,
                         const float* __restrict__ w1, bf16* __restrict__ w1t,
                         const float* __restrict__ w2, bf16* __restrict__ w2t,
                         const int* __restrict__ eidx, int* __restrict__ blockhist) {
  int bid = blockIdx.x;
  int tid = threadIdx.x;
  if (bid < NB_CONV) {                       // ---- x f32 -> bf16
    int gid = bid * 256 + tid;
    float4 v = ((const float4*)x)[gid];
    alignas(8) bf16 o[4];
    o[0] = __float2bfloat16(v.x); o[1] = __float2bfloat16(v.y);
    o[2] = __float2bfloat16(v.z); o[3] = __float2bfloat16(v.w);
    ((ushort4*)xb)[gid] = *(const ushort4*)o;
  } else if (bid < NB_CONV + NB_W1) {        // ---- w1 [E][HS][FFN] -> [E][FFN][HS]
    transpose_body<HSD, FFND>(w1, w1t, bid - NB_CONV, tid);
  } else if (bid < NB_CONV + NB_W1 + NB_W2) {// ---- w2 [E][FFN][HS] -> [E][HS][FFN]
    transpose_body<FFND, HSD>(w2, w2t, bid - NB_CONV - NB_W1, tid);
  } else {                                   // ---- expert histogram (64 blocks)
    __shared__ int h[NEXP];
    int b = bid - NB_CONV - NB_W1 - NB_W2;
    if (tid < NEXP) h[tid] = 0;
    __syncthreads();
    int gid = b * 256 + tid;
    atomicAdd(&h[eidx[gid] & 7], 1);
    __syncthreads();
    if (tid < NEXP) blockhist[b * NEXP + tid] = h[tid];
  }
}

// ================= routing plan (parallelized; LDS-resident) =================
__global__ void moe_plan(const int* __restrict__ blockhist, int* __restrict__ blockbase,
                         int* __restrict__ sched_e, int* __restrict__ sched_r,
                         int* __restrict__ ntiles,
                         int* __restrict__ stok, float* __restrict__ swt) {
  __shared__ int h[64 * NEXP];               // 2 KB copy of blockhist
  __shared__ int cnt[NEXP], off[NEXP];
  int tid = threadIdx.x;
  for (int i = tid; i < NRP; i += 256) { stok[i] = 0; swt[i] = 0.0f; }
  for (int i = tid; i < 64 * NEXP; i += 256) h[i] = blockhist[i];
  __syncthreads();
  if (tid < NEXP) {                          // per-expert totals from LDS
    int c = 0;
    #pragma unroll
    for (int b = 0; b < 64; ++b) c += h[b * NEXP + tid];
    cnt[tid] = c;
  }
  __syncthreads();
  if (tid == 0) {                            // tiny serial schedule (LDS only)
    int run = 0, it = 0;
    for (int e = 0; e < NEXP; ++e) {
      off[e] = run;
      int nt = (cnt[e] + 255) >> 8;          // 256-row tiles
      for (int j = 0; j < nt; ++j) { sched_e[it] = e; sched_r[it] = run + j * 256; ++it; }
      run += nt << 8;
    }
    *ntiles = it;
  }
  __syncthreads();
  if (tid < NEXP) {                          // per-expert prefix over 64 blocks (LDS)
    int r = off[tid];
    #pragma unroll
    for (int b = 0; b < 64; ++b) { blockbase[b * NEXP + tid] = r; r += h[b * NEXP + tid]; }
  }
}

__global__ void moe_scatter(const int* __restrict__ eidx, const float* __restrict__ ew,
                            const int* __restrict__ blockbase,
                            int* __restrict__ stok, float* __restrict__ swt,
                            int* __restrict__ slot) {
  __shared__ int cur[NEXP];
  int tid = threadIdx.x;
  if (tid < NEXP) cur[tid] = blockbase[blockIdx.x * NEXP + tid];
  __syncthreads();
  int gid = blockIdx.x * 256 + tid;
  int e = eidx[gid] & 7;
  int pos = atomicAdd(&cur[e], 1);
  stok[pos] = gid >> 1;          // token = gid / NTOP
  swt[pos]  = ew[gid];
  slot[gid] = pos;
}

// ================= grouped GEMM: 256x256 8-phase schedule (m201 template) =====
// 8 waves (2M x 4N), per-wave C = 128x64.  LDS = 2 K-tile buffers x 64KB.
// Per iteration j (tiles 2j->buf0, 2j+1->buf1), 8 phases; each phase:
//   [ds-read quadrant frags | stage 1 half-tile] -> barrier -> 16 MFMA -> barrier
// Counted s_waitcnt vmcnt(4) only at p3/p7 (checkpoints; never drain to 0 in
// steady state).  NEW (R3): bijective XCD swizzle (T1) of the flattened block
// index so same-XCD blocks share A row-panels and expert B panels in L2.
template<int KDIM, int NDIM, int NSPLIT, bool GATHER, int ACT, int GX, int NWG>
__global__ __launch_bounds__(512, 2)
void moe_gemm(const bf16* __restrict__ A, const bf16* __restrict__ B,
              bf16* __restrict__ OutBase,
              const int* __restrict__ stok,
              const int* __restrict__ sched_e, const int* __restrict__ sched_r,
              const int* __restrict__ ntiles) {
  constexpr int BM = 256, BN = 256, BK = 64;
  constexpr int BUFS = (BM + BN) * BK;        // 32768 shorts = 64 KB per K-tile
  constexpr int KT = KDIM / BK / NSPLIT;      // 16 (GEMM1) / 32 (GEMM2)
  constexpr int JT = KT / 2;
  static_assert(NWG % 8 == 0, "XCD swizzle needs nwg % 8 == 0");
  constexpr unsigned Q = NWG / 8;

  // ---- XCD-aware bijective remap of (x, rt, z) ----
  unsigned flat = (blockIdx.z * MAXT + blockIdx.y) * GX + blockIdx.x;
  unsigned nf = (flat & 7) * Q + (flat >> 3);
  const int bx = nf % GX;
  unsigned t2 = nf / GX;
  const int rt = t2 % MAXT;
  const int z  = t2 / MAXT;

  if (rt >= *ntiles) return;
  const int tid  = threadIdx.x;
  const int lane = tid & 63;
  const int wid  = tid >> 6;                  // 0..7
  const int wm = wid & 1, wn = wid >> 1;      // 2M x 4N
  const int e    = sched_e[rt];
  const int row0 = sched_r[rt];
  const int n0   = bx * BN;
  const int kbase = z * (KDIM / NSPLIT);
  bf16* Out = OutBase + (size_t)z * NRP * NDIM;

  __shared__ short lds[2 * BUFS];             // 128 KB

  const int l15  = lane & 15;
  const int quad = lane >> 4;
  const int xor7 = l15 & 7;
  const ushort* Aus  = (const ushort*)A;
  const ushort* Bexp = (const ushort*)B + (size_t)e * NDIM * KDIM;

  // ---- staging pointers (coalesced; swizzle folded into global k-offset) ----
  const int rsub  = lane >> 3;                 // row within 8-row chunk
  const int kgsrc = (lane & 7) ^ rsub;         // granule permutation (same line)
  const ushort* aP[2][2];                      // [half][q]
  const ushort* bP[2][2];
  #pragma unroll
  for (int h = 0; h < 2; ++h)
    #pragma unroll
    for (int q = 0; q < 2; ++q) {
      int xr = 128 * h + 8 * (2 * wid + q) + rsub;
      int grow = GATHER ? stok[row0 + xr] : (row0 + xr);
      aP[h][q] = Aus  + (size_t)grow * KDIM + kbase + kgsrc * 8;
      bP[h][q] = Bexp + (size_t)(n0 + xr) * KDIM + kbase + kgsrc * 8;
    }

  // stage one A/B half-tile of K-tile T into buffer b (2 x gload_lds16/thread)
  auto SA = [&](int b, int h, int T) {
    #pragma unroll
    for (int q = 0; q < 2; ++q)
      gload_lds16(aP[h][q] + T * 64, lds + b * BUFS + h * 8192 + (2 * wid + q) * 512);
  };
  auto SB = [&](int b, int h, int T) {
    #pragma unroll
    for (int q = 0; q < 2; ++q)
      gload_lds16(bP[h][q] + T * 64, lds + b * BUFS + BM * BK + h * 8192 + (2 * wid + q) * 512);
  };

  // ---- compute-side LDS addressing (shorts) ----
  const int goff0 = (quad ^ xor7) << 3;            // k-slice 0 granule offset
  const int goff1 = ((4 + quad) ^ xor7) << 3;      // k-slice 1
  const int mbase = (wm * 128 + l15) * 64;         // A rows base
  const int nbase = BM * BK + (wn * 64 + l15) * 64;// B region base

  f4v acc[8][4];
  #pragma unroll
  for (int mt = 0; mt < 8; ++mt)
    #pragma unroll
    for (int nt = 0; nt < 4; ++nt) acc[mt][nt] = (f4v)0.0f;

  b8v aF[2][4], bF0[2][2], bF1[2][2];

  auto LDA = [&](int b, int qm) {
    const short* base = lds + b * BUFS + mbase + qm * 4096;
    #pragma unroll
    for (int t = 0; t < 4; ++t) {
      aF[0][t] = *(const b8v*)(base + t * 1024 + goff0);
      aF[1][t] = *(const b8v*)(base + t * 1024 + goff1);
    }
  };
  auto LDB = [&](int b, int qn, b8v (&bF)[2][2]) {
    const short* base = lds + b * BUFS + nbase + qn * 2048;
    #pragma unroll
    for (int u = 0; u < 2; ++u) {
      bF[0][u] = *(const b8v*)(base + u * 1024 + goff0);
      bF[1][u] = *(const b8v*)(base + u * 1024 + goff1);
    }
  };
  auto MM = [&](int qm, int qn, b8v (&bF)[2][2]) {
    __builtin_amdgcn_s_setprio(1);
    #pragma unroll
    for (int s = 0; s < 2; ++s)
      #pragma unroll
      for (int t = 0; t < 4; ++t)
        #pragma unroll
        for (int u = 0; u < 2; ++u)
          acc[qm * 4 + t][qn * 2 + u] = mfma16(aF[s][t], bF[s][u], acc[qm * 4 + t][qn * 2 + u]);
    __builtin_amdgcn_s_setprio(0);
  };
  auto BAR = [&] {
    asm volatile("" ::: "memory");
    __builtin_amdgcn_s_barrier();
    asm volatile("" ::: "memory");
  };

  // ---- prologue: tile0 full + tile1 B-halves (steady-state p2..p7 of iter -1)
  SB(0, 0, 0); SB(0, 1, 0); SA(0, 0, 0); SA(0, 1, 0);
  SB(1, 0, 1); SB(1, 1, 1);
  asm volatile("s_waitcnt vmcnt(4)" ::: "memory");   // tile0 halves landed
  __builtin_amdgcn_s_barrier();
  asm volatile("" ::: "memory");

  #pragma unroll 1
  for (int j = 0; j < JT; ++j) {
    const int t1 = 2 * j + 1, t2i = 2 * j + 2, t3 = 2 * j + 3;
    const bool more = (j + 1 < JT);
    // ---- p0: buf0 quad (0,0); stage b1.A0 <- t1
    LDA(0, 0); LDB(0, 0, bF0);
    SA(1, 0, t1);
    BAR(); MM(0, 0, bF0); BAR();
    // ---- p1: buf0 quad (0,1); stage b1.A1 <- t1
    LDB(0, 1, bF1);
    SA(1, 1, t1);
    BAR(); MM(0, 1, bF1); BAR();
    // ---- p2: buf0 quad (1,1); stage b0.B0 <- t2
    LDA(0, 1);
    if (more) SB(0, 0, t2i);
    BAR(); MM(1, 1, bF1); BAR();
    // ---- p3: buf0 quad (1,0); stage b0.B1 <- t2; checkpoint
    if (more) SB(0, 1, t2i);
    BAR(); MM(1, 0, bF0);
    if (more) asm volatile("s_waitcnt vmcnt(4)" ::: "memory");
    else      asm volatile("s_waitcnt vmcnt(0)" ::: "memory");
    BAR();
    // ---- p4: buf1 quad (0,0); stage b0.A0 <- t2
    LDA(1, 0); LDB(1, 0, bF0);
    if (more) SA(0, 0, t2i);
    BAR(); MM(0, 0, bF0); BAR();
    // ---- p5: buf1 quad (0,1); stage b0.A1 <- t2
    LDB(1, 1, bF1);
    if (more) SA(0, 1, t2i);
    BAR(); MM(0, 1, bF1); BAR();
    // ---- p6: buf1 quad (1,1); stage b1.B0 <- t3
    LDA(1, 1);
    if (more) SB(1, 0, t3);
    BAR(); MM(1, 1, bF1); BAR();
    // ---- p7: buf1 quad (1,0); stage b1.B1 <- t3; checkpoint
    if (more) SB(1, 1, t3);
    BAR(); MM(1, 0, bF0);
    asm volatile("s_waitcnt vmcnt(4)" ::: "memory");
    BAR();
  }

  // epilogue: C/D layout row=(lane>>4)*4+reg, col=lane&15  [m89-verified]
  #pragma unroll
  for (int mt = 0; mt < 8; ++mt)
    #pragma unroll
    for (int nt = 0; nt < 4; ++nt) {
      f4v v = acc[mt][nt];
      #pragma unroll
      for (int r = 0; r < 4; ++r) {
        int m = row0 + wm * 128 + mt * 16 + quad * 4 + r;
        int n = n0   + wn * 64  + nt * 16 + l15;
        float o = (ACT == 0) ? gelu_tanh(v[r]) : v[r];
        Out[(size_t)m * NDIM + n] = __float2bfloat16(o);
      }
    }
}

// ================= combine =================
// out[t] = swt[s0]*(Yp0[s0]+Yp1[s0]) + swt[s1]*(Yp0[s1]+Yp1[s1])
__global__ void moe_combine(const bf16* __restrict__ Yp, const float* __restrict__ swt,
                            const int* __restrict__ slot, float* __restrict__ out) {
  int gid = blockIdx.x * 256 + threadIdx.x;   // NTOK*HSD/8 threads
  int t  = gid >> 7;
  int ho = (gid & 127) << 3;
  int s0 = slot[t * 2], s1 = slot[t * 2 + 1];
  float w0 = swt[s0], w1 = swt[s1];
  const __bf16* Y0 = (const __bf16*)Yp;
  const __bf16* Y1 = Y0 + (size_t)NRP * HSD;
  b8v a0 = *(const b8v*)(Y0 + (size_t)s0 * HSD + ho);
  b8v a1 = *(const b8v*)(Y1 + (size_t)s0 * HSD + ho);
  b8v b0 = *(const b8v*)(Y0 + (size_t)s1 * HSD + ho);
  b8v b1 = *(const b8v*)(Y1 + (size_t)s1 * HSD + ho);
  float o[8];
  #pragma unroll
  for (int i = 0; i < 8; ++i)
    o[i] = w0 * ((float)a0[i] + (float)a1[i]) + w1 * ((float)b0[i] + (float)b1[i]);
  float4* op = (float4*)(out + (size_t)t * HSD + ho);
  op[0] = make_float4(o[0], o[1], o[2], o[3]);
  op[1] = make_float4(o[4], o[5], o[6], o[7]);
}

// ================= launch =================
extern "C" void kernel_launch(void* const* d_in, const int* in_sizes, int n_in,
                              void* d_out, int out_size, void* d_ws, size_t ws_size,
                              hipStream_t stream) {
  const float* x    = (const float*)d_in[0];
  const float* ew   = (const float*)d_in[1];
  const float* w1   = (const float*)d_in[2];
  const float* w2   = (const float*)d_in[3];
  const int*   eidx = (const int*)d_in[4];
  float* out = (float*)d_out;
  char* ws = (char*)d_ws;

  if (ws_size < WS_NEED) {              // sentinel: absmax ~3.4e38 => ws too small
    hipMemsetAsync(d_out, 0x7F, 8, stream);
    return;
  }

  int*   blockhist = (int*)(ws + OFF_BLOCKHIST);
  int*   blockbase = (int*)(ws + OFF_BLOCKBASE);
  int*   sched_e   = (int*)(ws + OFF_SCHED_E);
  int*   sched_r   = (int*)(ws + OFF_SCHED_R);
  int*   ntiles    = (int*)(ws + OFF_NTILES);
  int*   stok      = (int*)(ws + OFF_STOK);
  float* swt       = (float*)(ws + OFF_SWT);
  int*   slot      = (int*)(ws + OFF_SLOT);
  bf16*  xb        = (bf16*)(ws + OFF_XB);
  bf16*  w1t       = (bf16*)(ws + OFF_W1T);
  bf16*  w2t       = (bf16*)(ws + OFF_W2T);
  bf16*  Hbuf      = (bf16*)(ws + OFF_H);
  bf16*  Ypart     = (bf16*)(ws + OFF_YP);   // aliases xb/w1t (dead after GEMM1)

  // fused prep: conv_x + w1^T + w2^T + hist (one launch)
  moe_prep<<<NB_PREP, 256, 0, stream>>>(x, xb, w1, w1t, w2, w2t, eidx, blockhist);
  moe_plan<<<1, 256, 0, stream>>>(blockhist, blockbase, sched_e, sched_r, ntiles, stok, swt);
  moe_scatter<<<64, 256, 0, stream>>>(eidx, ew, blockbase, stok, swt, slot);

  // GEMM1: H = gelu(X @ W1), gathered rows, K=1024, 256x256 tiles, 8-phase
  moe_gemm<HSD, FFND, 1, true, 0, FFND/256, (FFND/256)*MAXT>
      <<<dim3(FFND / 256, MAXT, 1), 512, 0, stream>>>(
      xb, w1t, Hbuf, stok, sched_e, sched_r, ntiles);
  // GEMM2: Yp[z] = H @ W2 (split-K=2 partials, unweighted), 256x256 tiles, 8-phase
  moe_gemm<FFND, HSD, 2, false, 1, HSD/256, (HSD/256)*MAXT*2>
      <<<dim3(HSD / 256, MAXT, 2), 512, 0, stream>>>(
      Hbuf, w2t, Ypart, stok, sched_e, sched_r, ntiles);

  moe_combine<<<NTOK * HSD / 8 / 256, 256, 0, stream>>>(Ypart, swt, slot, out);
}

// Round 4
// 697.412 us; speedup vs baseline: 1.1233x; 1.0061x over previous
//
#include <hip/hip_runtime.h>
#include <hip/hip_bf16.h>
#include <stdint.h>
#include <stddef.h>

// Problem constants (from reference)
#define SLEN 2048
#define BSZ  4
#define HSD  1024
#define FFND 4096
#define NEXP 8
#define NTOP 2
#define NTOK (SLEN*BSZ)        // 8192 tokens
#define NROW (NTOK*NTOP)       // 16384 (token,k) rows
#define NRP  (NROW + NEXP*256) // 18432 padded row capacity (256-row tiles)
#define MAXT (NROW/256 + NEXP) // 72 max 256-row tiles

typedef __hip_bfloat16 bf16;
typedef __attribute__((ext_vector_type(8))) __bf16 b8v;   // MFMA A/B frag (4 VGPR)
typedef __attribute__((ext_vector_type(4))) float f4v;    // MFMA C/D frag

// ---- workspace layout (bytes) ----
static constexpr size_t OFF_BLOCKHIST = 0;                        // int[64][8]
static constexpr size_t OFF_BLOCKBASE = 2048;                     // int[64][8]
static constexpr size_t OFF_SCHED_E   = 4096;                     // int[<=160]
static constexpr size_t OFF_SCHED_R   = 4736;                     // int[<=160]
static constexpr size_t OFF_NTILES    = 5376;                     // int
static constexpr size_t OFF_STOK      = 8192;                     // int[NRP]   (73728 B)
static constexpr size_t OFF_SWT       = OFF_STOK + 73728;         // float[NRP] (73728 B)
static constexpr size_t OFF_SLOT      = OFF_SWT + 73728;          // int[NROW]  (65536 B) -> ends 221184
static constexpr size_t OFF_XB        = 221184;                   // bf16[NTOK][HSD]
static constexpr size_t OFF_W1T       = OFF_XB  + (size_t)NTOK*HSD*2;        // bf16[E][FFN][HS]
static constexpr size_t OFF_W2T       = OFF_W1T + (size_t)NEXP*FFND*HSD*2;   // bf16[E][HS][FFN]
static constexpr size_t OFF_H         = OFF_W2T + (size_t)NEXP*HSD*FFND*2;   // bf16[NRP][FFN]
static constexpr size_t WS_NEED       = OFF_H   + (size_t)NRP*FFND*2;        // ~302 MiB
// Split-K partials alias the xb+w1t region (dead after GEMM1):
//   Yp = bf16[2][NRP][HSD] = 75.5 MB  <=  xb(16.8) + w1t(67.1) = 83.9 MB  OK (w2t untouched)
static constexpr size_t OFF_YP        = OFF_XB;

// ---- helpers ----
__device__ __forceinline__ void gload_lds16(const void* g, void* l) {
  __builtin_amdgcn_global_load_lds(
      (const __attribute__((address_space(1))) unsigned int*)g,
      (__attribute__((address_space(3))) unsigned int*)l, 16, 0, 0);
}

__device__ __forceinline__ f4v mfma16(b8v a, b8v b, f4v c) {
  return __builtin_amdgcn_mfma_f32_16x16x32_bf16(a, b, c, 0, 0, 0);
}

// gelu tanh-approx via exact identity 0.5x(1+tanh(u)) = x*sigmoid(2u).
// 2u = 1.5957691216x + 0.0713548162x^3.  Safe at +/-inf (x/(1+inf) -> -0).
__device__ __forceinline__ float gelu_fast(float x) {
  float u2 = x * (1.5957691216057308f + 0.07135481627286064f * x * x);
  return x / (1.0f + __expf(-u2));
}

// ================= fused prep: conv_x + w1^T + w2^T + hist =================
#define NB_CONV (NTOK*HSD/4/256)                 // 8192
#define NB_W1   (NEXP*(HSD/64)*(FFND/32))        // 16384
#define NB_W2   (NEXP*(FFND/64)*(HSD/32))        // 16384
#define NB_HIST 64
#define NB_PREP (NB_CONV + NB_W1 + NB_W2 + NB_HIST)

template<int R, int C>
__device__ __forceinline__ void transpose_body(const float* __restrict__ src,
                                               bf16* __restrict__ dst,
                                               int l, int tid) {
  __shared__ float tile[32][65];          // [col][row], pad breaks 64-stride
  constexpr int CT = C / 32, RT = R / 64;          // both pow2
  int e   = l / (CT * RT);
  int rem = l - e * (CT * RT);
  int by  = rem / CT, bx = rem % CT;
  const float* s = src + (size_t)e * R * C;
  uint* d = (uint*)((ushort*)dst + (size_t)e * R * C);
  int c0 = bx * 32, r0 = by * 64;
  int tx = tid & 31, ty = tid >> 5;        // 32 x 8
  #pragma unroll
  for (int j = 0; j < 64; j += 8)
    tile[tx][ty + j] = s[(size_t)(r0 + ty + j) * C + (c0 + tx)];
  __syncthreads();
  #pragma unroll
  for (int j = 0; j < 32; j += 8) {
    int c = ty + j;
    alignas(4) bf16 p[2];
    p[0] = __float2bfloat16(tile[c][tx * 2]);
    p[1] = __float2bfloat16(tile[c][tx * 2 + 1]);
    d[(((size_t)(c0 + c) * R + r0) >> 1) + tx] = *(const uint*)p;
  }
}

__global__ void moe_prep(const float* __restrict__ x, bf16* __restrict__ xb,
                         const float* __restrict__ w1, bf16* __restrict__ w1t,
                         const float* __restrict__ w2, bf16* __restrict__ w2t,
                         const int* __restrict__ eidx, int* __restrict__ blockhist) {
  int bid = blockIdx.x;
  int tid = threadIdx.x;
  if (bid < NB_CONV) {                       // ---- x f32 -> bf16
    int gid = bid * 256 + tid;
    float4 v = ((const float4*)x)[gid];
    alignas(8) bf16 o[4];
    o[0] = __float2bfloat16(v.x); o[1] = __float2bfloat16(v.y);
    o[2] = __float2bfloat16(v.z); o[3] = __float2bfloat16(v.w);
    ((ushort4*)xb)[gid] = *(const ushort4*)o;
  } else if (bid < NB_CONV + NB_W1) {        // ---- w1 [E][HS][FFN] -> [E][FFN][HS]
    transpose_body<HSD, FFND>(w1, w1t, bid - NB_CONV, tid);
  } else if (bid < NB_CONV + NB_W1 + NB_W2) {// ---- w2 [E][FFN][HS] -> [E][HS][FFN]
    transpose_body<FFND, HSD>(w2, w2t, bid - NB_CONV - NB_W1, tid);
  } else {                                   // ---- expert histogram (64 blocks)
    __shared__ int h[NEXP];
    int b = bid - NB_CONV - NB_W1 - NB_W2;
    if (tid < NEXP) h[tid] = 0;
    __syncthreads();
    int gid = b * 256 + tid;
    atomicAdd(&h[eidx[gid] & 7], 1);
    __syncthreads();
    if (tid < NEXP) blockhist[b * NEXP + tid] = h[tid];
  }
}

// ================= routing plan (parallelized; LDS-resident) =================
__global__ void moe_plan(const int* __restrict__ blockhist, int* __restrict__ blockbase,
                         int* __restrict__ sched_e, int* __restrict__ sched_r,
                         int* __restrict__ ntiles,
                         int* __restrict__ stok, float* __restrict__ swt) {
  __shared__ int h[64 * NEXP];               // 2 KB copy of blockhist
  __shared__ int cnt[NEXP], off[NEXP];
  int tid = threadIdx.x;
  for (int i = tid; i < NRP; i += 256) { stok[i] = 0; swt[i] = 0.0f; }
  for (int i = tid; i < 64 * NEXP; i += 256) h[i] = blockhist[i];
  __syncthreads();
  if (tid < NEXP) {                          // per-expert totals from LDS
    int c = 0;
    #pragma unroll
    for (int b = 0; b < 64; ++b) c += h[b * NEXP + tid];
    cnt[tid] = c;
  }
  __syncthreads();
  if (tid == 0) {                            // tiny serial schedule (LDS only)
    int run = 0, it = 0;
    for (int e = 0; e < NEXP; ++e) {
      off[e] = run;
      int nt = (cnt[e] + 255) >> 8;          // 256-row tiles
      for (int j = 0; j < nt; ++j) { sched_e[it] = e; sched_r[it] = run + j * 256; ++it; }
      run += nt << 8;
    }
    *ntiles = it;
  }
  __syncthreads();
  if (tid < NEXP) {                          // per-expert prefix over 64 blocks (LDS)
    int r = off[tid];
    #pragma unroll
    for (int b = 0; b < 64; ++b) { blockbase[b * NEXP + tid] = r; r += h[b * NEXP + tid]; }
  }
}

__global__ void moe_scatter(const int* __restrict__ eidx, const float* __restrict__ ew,
                            const int* __restrict__ blockbase,
                            int* __restrict__ stok, float* __restrict__ swt,
                            int* __restrict__ slot) {
  __shared__ int cur[NEXP];
  int tid = threadIdx.x;
  if (tid < NEXP) cur[tid] = blockbase[blockIdx.x * NEXP + tid];
  __syncthreads();
  int gid = blockIdx.x * 256 + tid;
  int e = eidx[gid] & 7;
  int pos = atomicAdd(&cur[e], 1);
  stok[pos] = gid >> 1;          // token = gid / NTOP
  swt[pos]  = ew[gid];
  slot[gid] = pos;
}

// ================= grouped GEMM: 256x256 8-phase schedule (m201 template) =====
// 8 waves (2M x 4N), per-wave C = 128x64.  LDS = 2 K-tile buffers x 64KB.
// Per phase: [ds-read quadrant frags | stage 1 half-tile] -> barrier -> 16 MFMA
// -> barrier.  Counted s_waitcnt vmcnt(4) only at p3/p7.
// R4: (a) XCD swizzle reverted (hurt: FETCH 165->175 MB, L3-fit regime);
//     (b) epilogue staged through LDS: 128 scattered 2-B stores/thread ->
//         16 coalesced 16-B stores (128-B contiguous per 8 lanes);
//     (c) gelu via sigmoid identity (~9 VALU vs ~12).
template<int KDIM, int NDIM, int NSPLIT, bool GATHER, int ACT>
__global__ __launch_bounds__(512, 2)
void moe_gemm(const bf16* __restrict__ A, const bf16* __restrict__ B,
              bf16* __restrict__ OutBase,
              const int* __restrict__ stok,
              const int* __restrict__ sched_e, const int* __restrict__ sched_r,
              const int* __restrict__ ntiles) {
  constexpr int BM = 256, BN = 256, BK = 64;
  constexpr int BUFS = (BM + BN) * BK;        // 32768 shorts = 64 KB per K-tile
  constexpr int KT = KDIM / BK / NSPLIT;      // 16 (GEMM1) / 32 (GEMM2)
  constexpr int JT = KT / 2;

  int rt = blockIdx.y;
  if (rt >= *ntiles) return;
  const int tid  = threadIdx.x;
  const int lane = tid & 63;
  const int wid  = tid >> 6;                  // 0..7
  const int wm = wid & 1, wn = wid >> 1;      // 2M x 4N
  const int e    = sched_e[rt];
  const int row0 = sched_r[rt];
  const int n0   = blockIdx.x * BN;
  const int z    = blockIdx.z;
  const int kbase = z * (KDIM / NSPLIT);
  bf16* Out = OutBase + (size_t)z * NRP * NDIM;

  __shared__ short lds[2 * BUFS];             // 128 KB

  const int l15  = lane & 15;
  const int quad = lane >> 4;
  const int xor7 = l15 & 7;
  const ushort* Aus  = (const ushort*)A;
  const ushort* Bexp = (const ushort*)B + (size_t)e * NDIM * KDIM;

  // ---- staging pointers (coalesced; swizzle folded into global k-offset) ----
  const int rsub  = lane >> 3;                 // row within 8-row chunk
  const int kgsrc = (lane & 7) ^ rsub;         // granule permutation (same line)
  const ushort* aP[2][2];                      // [half][q]
  const ushort* bP[2][2];
  #pragma unroll
  for (int h = 0; h < 2; ++h)
    #pragma unroll
    for (int q = 0; q < 2; ++q) {
      int xr = 128 * h + 8 * (2 * wid + q) + rsub;
      int grow = GATHER ? stok[row0 + xr] : (row0 + xr);
      aP[h][q] = Aus  + (size_t)grow * KDIM + kbase + kgsrc * 8;
      bP[h][q] = Bexp + (size_t)(n0 + xr) * KDIM + kbase + kgsrc * 8;
    }

  // stage one A/B half-tile of K-tile T into buffer b (2 x gload_lds16/thread)
  auto SA = [&](int b, int h, int T) {
    #pragma unroll
    for (int q = 0; q < 2; ++q)
      gload_lds16(aP[h][q] + T * 64, lds + b * BUFS + h * 8192 + (2 * wid + q) * 512);
  };
  auto SB = [&](int b, int h, int T) {
    #pragma unroll
    for (int q = 0; q < 2; ++q)
      gload_lds16(bP[h][q] + T * 64, lds + b * BUFS + BM * BK + h * 8192 + (2 * wid + q) * 512);
  };

  // ---- compute-side LDS addressing (shorts) ----
  const int goff0 = (quad ^ xor7) << 3;            // k-slice 0 granule offset
  const int goff1 = ((4 + quad) ^ xor7) << 3;      // k-slice 1
  const int mbase = (wm * 128 + l15) * 64;         // A rows base
  const int nbase = BM * BK + (wn * 64 + l15) * 64;// B region base

  f4v acc[8][4];
  #pragma unroll
  for (int mt = 0; mt < 8; ++mt)
    #pragma unroll
    for (int nt = 0; nt < 4; ++nt) acc[mt][nt] = (f4v)0.0f;

  b8v aF[2][4], bF0[2][2], bF1[2][2];

  auto LDA = [&](int b, int qm) {
    const short* base = lds + b * BUFS + mbase + qm * 4096;
    #pragma unroll
    for (int t = 0; t < 4; ++t) {
      aF[0][t] = *(const b8v*)(base + t * 1024 + goff0);
      aF[1][t] = *(const b8v*)(base + t * 1024 + goff1);
    }
  };
  auto LDB = [&](int b, int qn, b8v (&bF)[2][2]) {
    const short* base = lds + b * BUFS + nbase + qn * 2048;
    #pragma unroll
    for (int u = 0; u < 2; ++u) {
      bF[0][u] = *(const b8v*)(base + u * 1024 + goff0);
      bF[1][u] = *(const b8v*)(base + u * 1024 + goff1);
    }
  };
  auto MM = [&](int qm, int qn, b8v (&bF)[2][2]) {
    __builtin_amdgcn_s_setprio(1);
    #pragma unroll
    for (int s = 0; s < 2; ++s)
      #pragma unroll
      for (int t = 0; t < 4; ++t)
        #pragma unroll
        for (int u = 0; u < 2; ++u)
          acc[qm * 4 + t][qn * 2 + u] = mfma16(aF[s][t], bF[s][u], acc[qm * 4 + t][qn * 2 + u]);
    __builtin_amdgcn_s_setprio(0);
  };
  auto BAR = [&] {
    asm volatile("" ::: "memory");
    __builtin_amdgcn_s_barrier();
    asm volatile("" ::: "memory");
  };

  // ---- prologue: tile0 full + tile1 B-halves (steady-state p2..p7 of iter -1)
  SB(0, 0, 0); SB(0, 1, 0); SA(0, 0, 0); SA(0, 1, 0);
  SB(1, 0, 1); SB(1, 1, 1);
  asm volatile("s_waitcnt vmcnt(4)" ::: "memory");   // tile0 halves landed
  __builtin_amdgcn_s_barrier();
  asm volatile("" ::: "memory");

  #pragma unroll 1
  for (int j = 0; j < JT; ++j) {
    const int t1 = 2 * j + 1, t2i = 2 * j + 2, t3 = 2 * j + 3;
    const bool more = (j + 1 < JT);
    // ---- p0: buf0 quad (0,0); stage b1.A0 <- t1
    LDA(0, 0); LDB(0, 0, bF0);
    SA(1, 0, t1);
    BAR(); MM(0, 0, bF0); BAR();
    // ---- p1: buf0 quad (0,1); stage b1.A1 <- t1
    LDB(0, 1, bF1);
    SA(1, 1, t1);
    BAR(); MM(0, 1, bF1); BAR();
    // ---- p2: buf0 quad (1,1); stage b0.B0 <- t2
    LDA(0, 1);
    if (more) SB(0, 0, t2i);
    BAR(); MM(1, 1, bF1); BAR();
    // ---- p3: buf0 quad (1,0); stage b0.B1 <- t2; checkpoint
    if (more) SB(0, 1, t2i);
    BAR(); MM(1, 0, bF0);
    if (more) asm volatile("s_waitcnt vmcnt(4)" ::: "memory");
    else      asm volatile("s_waitcnt vmcnt(0)" ::: "memory");
    BAR();
    // ---- p4: buf1 quad (0,0); stage b0.A0 <- t2
    LDA(1, 0); LDB(1, 0, bF0);
    if (more) SA(0, 0, t2i);
    BAR(); MM(0, 0, bF0); BAR();
    // ---- p5: buf1 quad (0,1); stage b0.A1 <- t2
    LDB(1, 1, bF1);
    if (more) SA(0, 1, t2i);
    BAR(); MM(0, 1, bF1); BAR();
    // ---- p6: buf1 quad (1,1); stage b1.B0 <- t3
    LDA(1, 1);
    if (more) SB(1, 0, t3);
    BAR(); MM(1, 1, bF1); BAR();
    // ---- p7: buf1 quad (1,0); stage b1.B1 <- t3; checkpoint
    if (more) SB(1, 1, t3);
    BAR(); MM(1, 0, bF0);
    asm volatile("s_waitcnt vmcnt(4)" ::: "memory");
    BAR();
  }

  // ---- epilogue via LDS slab: coalesced stores ----
  // After the final p7 BAR all waves' LDS reads are retired -> buffers dead.
  // Per-wave private slab: 64 rows x stride 72 shorts (144 B, 16B-aligned;
  // read-side conflict-free, write-side ~4-way on 2B writes).  Two m-halves.
  {
    constexpr int SST = 72;                   // slab row stride in shorts
    bf16* slab = (bf16*)(lds + wid * 4608);   // 64*72 = 4608 shorts per wave
    const int r8 = lane >> 3;                 // 0..7 row-in-group
    const int c8 = (lane & 7) * 8;            // col start (8 bf16 = 16 B)
    ushort* outb = (ushort*)Out;
    #pragma unroll
    for (int mh = 0; mh < 2; ++mh) {
      #pragma unroll
      for (int mt = 0; mt < 4; ++mt)
        #pragma unroll
        for (int nt = 0; nt < 4; ++nt) {
          f4v v = acc[mh * 4 + mt][nt];
          #pragma unroll
          for (int r = 0; r < 4; ++r) {
            float o = (ACT == 0) ? gelu_fast(v[r]) : v[r];
            slab[(mt * 16 + quad * 4 + r) * SST + nt * 16 + l15] = __float2bfloat16(o);
          }
        }
      // read back 8 rows/iter, store 16 B per lane (128-B contiguous per 8 lanes)
      #pragma unroll
      for (int i = 0; i < 8; ++i) {
        int r = i * 8 + r8;
        b8v vv = *(const b8v*)((const short*)slab + r * SST + c8);
        *(b8v*)(outb + (size_t)(row0 + wm * 128 + mh * 64 + r) * NDIM
                      + (n0 + wn * 64 + c8)) = vv;
      }
    }
  }
}

// ================= combine =================
// out[t] = swt[s0]*(Yp0[s0]+Yp1[s0]) + swt[s1]*(Yp0[s1]+Yp1[s1])
__global__ void moe_combine(const bf16* __restrict__ Yp, const float* __restrict__ swt,
                            const int* __restrict__ slot, float* __restrict__ out) {
  int gid = blockIdx.x * 256 + threadIdx.x;   // NTOK*HSD/8 threads
  int t  = gid >> 7;
  int ho = (gid & 127) << 3;
  int s0 = slot[t * 2], s1 = slot[t * 2 + 1];
  float w0 = swt[s0], w1 = swt[s1];
  const __bf16* Y0 = (const __bf16*)Yp;
  const __bf16* Y1 = Y0 + (size_t)NRP * HSD;
  b8v a0 = *(const b8v*)(Y0 + (size_t)s0 * HSD + ho);
  b8v a1 = *(const b8v*)(Y1 + (size_t)s0 * HSD + ho);
  b8v b0 = *(const b8v*)(Y0 + (size_t)s1 * HSD + ho);
  b8v b1 = *(const b8v*)(Y1 + (size_t)s1 * HSD + ho);
  float o[8];
  #pragma unroll
  for (int i = 0; i < 8; ++i)
    o[i] = w0 * ((float)a0[i] + (float)a1[i]) + w1 * ((float)b0[i] + (float)b1[i]);
  float4* op = (float4*)(out + (size_t)t * HSD + ho);
  op[0] = make_float4(o[0], o[1], o[2], o[3]);
  op[1] = make_float4(o[4], o[5], o[6], o[7]);
}

// ================= launch =================
extern "C" void kernel_launch(void* const* d_in, const int* in_sizes, int n_in,
                              void* d_out, int out_size, void* d_ws, size_t ws_size,
                              hipStream_t stream) {
  const float* x    = (const float*)d_in[0];
  const float* ew   = (const float*)d_in[1];
  const float* w1   = (const float*)d_in[2];
  const float* w2   = (const float*)d_in[3];
  const int*   eidx = (const int*)d_in[4];
  float* out = (float*)d_out;
  char* ws = (char*)d_ws;

  if (ws_size < WS_NEED) {              // sentinel: absmax ~3.4e38 => ws too small
    hipMemsetAsync(d_out, 0x7F, 8, stream);
    return;
  }

  int*   blockhist = (int*)(ws + OFF_BLOCKHIST);
  int*   blockbase = (int*)(ws + OFF_BLOCKBASE);
  int*   sched_e   = (int*)(ws + OFF_SCHED_E);
  int*   sched_r   = (int*)(ws + OFF_SCHED_R);
  int*   ntiles    = (int*)(ws + OFF_NTILES);
  int*   stok      = (int*)(ws + OFF_STOK);
  float* swt       = (float*)(ws + OFF_SWT);
  int*   slot      = (int*)(ws + OFF_SLOT);
  bf16*  xb        = (bf16*)(ws + OFF_XB);
  bf16*  w1t       = (bf16*)(ws + OFF_W1T);
  bf16*  w2t       = (bf16*)(ws + OFF_W2T);
  bf16*  Hbuf      = (bf16*)(ws + OFF_H);
  bf16*  Ypart     = (bf16*)(ws + OFF_YP);   // aliases xb/w1t (dead after GEMM1)

  // fused prep: conv_x + w1^T + w2^T + hist (one launch)
  moe_prep<<<NB_PREP, 256, 0, stream>>>(x, xb, w1, w1t, w2, w2t, eidx, blockhist);
  moe_plan<<<1, 256, 0, stream>>>(blockhist, blockbase, sched_e, sched_r, ntiles, stok, swt);
  moe_scatter<<<64, 256, 0, stream>>>(eidx, ew, blockbase, stok, swt, slot);

  // GEMM1: H = gelu(X @ W1), gathered rows, K=1024, 256x256 tiles, 8-phase
  moe_gemm<HSD, FFND, 1, true, 0><<<dim3(FFND / 256, MAXT, 1), 512, 0, stream>>>(
      xb, w1t, Hbuf, stok, sched_e, sched_r, ntiles);
  // GEMM2: Yp[z] = H @ W2 (split-K=2 partials, unweighted), 256x256 tiles, 8-phase
  moe_gemm<FFND, HSD, 2, false, 1><<<dim3(HSD / 256, MAXT, 2), 512, 0, stream>>>(
      Hbuf, w2t, Ypart, stok, sched_e, sched_r, ntiles);

  moe_combine<<<NTOK * HSD / 8 / 256, 256, 0, stream>>>(Ypart, swt, slot, out);
}